// Round 14
// baseline (229.290 us; speedup 1.0000x reference)
//
#include <hip/hip_runtime.h>
#include <math.h>

#define B_TOK 8192
#define H_DIM 7168
#define E_NUM 256
#define NKS   4
#define KSL   (H_DIM / NKS)    // 1792
#define BK    32
#define NSTEP (KSL / BK)       // 56 (even)
#define BM    128
#define NMT   (B_TOK / BM)     // 64
#define FLAG_CAP 512
#define TAU   2e-6

typedef _Float16 f16;
typedef __attribute__((ext_vector_type(8))) _Float16 f16x8;
typedef __attribute__((ext_vector_type(4))) float    f32x4;

typedef __attribute__((address_space(1))) const void gvoid_t;
typedef __attribute__((address_space(3))) void       lvoid_t;

__device__ inline void gload_lds16(const void* g, void* s) {
    __builtin_amdgcn_global_load_lds((gvoid_t*)g, (lvoid_t*)s, 16, 0, 0);
}

#define WAITVM(N) do { asm volatile("s_waitcnt vmcnt(" #N ")" ::: "memory"); \
                       __builtin_amdgcn_sched_barrier(0); } while (0)
#define WAITLGKM0() do { asm volatile("s_waitcnt lgkmcnt(0)" ::: "memory"); \
                       __builtin_amdgcn_sched_barrier(0); } while (0)

// ---------------------------------------------------------------------------
// Shared routing math (fp64, verified) + decision margins.
// ---------------------------------------------------------------------------
__device__ __forceinline__ void route_token(
    const double* lv, const double* bj, int l, int hf, int t,
    float* __restrict__ out, double* ming_adj, double* ming_grp)
{
    double m = fmax(fmax(lv[0], lv[1]), fmax(lv[2], lv[3]));
    #pragma unroll
    for (int d = 1; d < 64; d <<= 1) m = fmax(m, __shfl_xor(m, d, 64));
    double sc[4], zs = 0.0;
    #pragma unroll
    for (int q = 0; q < 4; ++q) { sc[q] = exp(lv[q] - m); zs += sc[q]; }
    #pragma unroll
    for (int d = 1; d < 64; d <<= 1) zs += __shfl_xor(zs, d, 64);
    double swb[4];
    #pragma unroll
    for (int q = 0; q < 4; ++q) { sc[q] /= zs; swb[q] = sc[q] + bj[q]; }

    double gsq[4];
    #pragma unroll
    for (int q = 0; q < 4; ++q) {
        double a = swb[q], b = -INFINITY;
        #pragma unroll
        for (int d = 1; d <= 16; d <<= 1) {
            double oa = __shfl_xor(a, d, 64), ob = __shfl_xor(b, d, 64);
            double na = fmax(a, oa);
            double nb = fmax(fmin(a, oa), fmax(b, ob));
            a = na; b = nb;
        }
        gsq[q] = a + b;
    }
    double gsv[8];
    #pragma unroll
    for (int q = 0; q < 4; ++q) {
        gsv[2 * q]     = __shfl(gsq[q], 0, 64);
        gsv[2 * q + 1] = __shfl(gsq[q], 32, 64);
    }

    unsigned selmask = 0; double g4 = 0.0, g5 = 0.0;
    #pragma unroll
    for (int k = 0; k < 5; ++k) {
        double best = -INFINITY; int bg = 0;
        #pragma unroll
        for (int g = 0; g < 8; ++g)
            if (gsv[g] > best) { best = gsv[g]; bg = g; }
        if (k < 4) { selmask |= 1u << bg; g4 = best; } else g5 = best;
        #pragma unroll
        for (int g = 0; g < 8; ++g) if (g == bg) gsv[g] = -INFINITY;
    }
    *ming_grp = g4 - g5;

    double mk[4];
    #pragma unroll
    for (int q = 0; q < 4; ++q)
        mk[q] = ((selmask >> (2 * q + hf)) & 1u) ? swb[q] : -INFINITY;

    double wk[8]; int ek[8]; double wsum = 0.0;
    double prev = 0.0, ming = 1e300;
    #pragma unroll
    for (int k = 0; k < 9; ++k) {
        double vbest = mk[0]; int ebest = l;
        #pragma unroll
        for (int q = 1; q < 4; ++q)
            if (mk[q] > vbest) { vbest = mk[q]; ebest = l + 64 * q; }
        #pragma unroll
        for (int d = 1; d < 64; d <<= 1) {
            double ov = __shfl_xor(vbest, d, 64);
            int    oe = __shfl_xor(ebest, d, 64);
            if (ov > vbest || (ov == vbest && oe < ebest)) { vbest = ov; ebest = oe; }
        }
        if (k > 0) ming = fmin(ming, prev - vbest);
        prev = vbest;
        if (k < 8) {
            const int ol = ebest & 63, oq = ebest >> 6;
            if (l == ol) {
                #pragma unroll
                for (int q = 0; q < 4; ++q) if (q == oq) mk[q] = -INFINITY;
            }
            double cand = (oq == 0) ? sc[0] : (oq == 1) ? sc[1] : (oq == 2) ? sc[2] : sc[3];
            double sv = __shfl(cand, ol, 64);
            wk[k] = sv; ek[k] = ebest; wsum += sv;
        }
    }
    *ming_adj = ming;

    if (l == 0) {
        const double inv = 1.0 / wsum;
        #pragma unroll
        for (int k = 0; k < 8; ++k) {
            out[(size_t)t * 8 + k] = (float)((wk[k] * inv + 1e-20) * 2.5);
            out[(size_t)B_TOK * 8 + (size_t)t * 8 + k] = (float)ek[k];
        }
    }
}

// ---------------------------------------------------------------------------
// Kernel 1: pack W -> MFMA-B-fragment-ordered f16 hi/lo, COALESCED writes.
// off = ((kf*16+nf)*2+h)*512 + l*8 + j.
// ---------------------------------------------------------------------------
__global__ void convert_w_kernel(const float* __restrict__ W,
                                 f16* __restrict__ wpk,
                                 unsigned* __restrict__ flags) {
    if (blockIdx.x == 0 && threadIdx.x == 0) flags[0] = 0;
    int gid = blockIdx.x * 256 + threadIdx.x;     // 0 .. 3584*64-1
    int fgp = gid >> 6;                           // kf*16 + nf
    int l   = gid & 63;
    int kf = fgp >> 4, nf = fgp & 15;
    int rb  = kf * 32 + (l >> 4) * 8;
    int col = nf * 16 + (l & 15);
    f16x8 hv, lv;
    #pragma unroll
    for (int j = 0; j < 8; ++j) {
        float v = W[(size_t)(rb + j) * E_NUM + col];
        f16 hh = (f16)v;
        hv[j] = hh;
        lv[j] = (f16)(v - (float)hh);
    }
    *reinterpret_cast<f16x8*>(&wpk[(size_t)fgp * 1024 + l * 8])       = hv;
    *reinterpret_cast<f16x8*>(&wpk[(size_t)fgp * 1024 + 512 + l * 8]) = lv;
}

// ---------------------------------------------------------------------------
// GEMM helpers (R10 verified-best structure, setprio restored per R10-vs-R13
// A/B: 135 vs 146 us)
// ---------------------------------------------------------------------------
__device__ __forceinline__ void stage_B(const f16* __restrict__ wpk, int kf,
                                        char* bbuf, int wid, int l) {
    #pragma unroll
    for (int i = 0; i < 4; ++i) {
        int fi = wid * 4 + i, nf = fi >> 1, h = fi & 1;
        const f16* src = wpk + ((size_t)(kf * 16 + nf) * 2 + h) * 512 + (size_t)l * 8;
        gload_lds16(src, bbuf + 16384 + (nf * 2 + h) * 1024);
    }
}

__device__ __forceinline__ void write_A(char* buf, int wid, int l,
                                        float4 a0, float4 a1) {
    float fv[8] = {a0.x, a0.y, a0.z, a0.w, a1.x, a1.y, a1.z, a1.w};
    f16x8 hv, lo;
    #pragma unroll
    for (int j = 0; j < 8; ++j) {
        f16 hh = (f16)fv[j];
        hv[j] = hh;
        lo[j] = (f16)(fv[j] - (float)hh);
    }
    *reinterpret_cast<f16x8*>(&buf[(wid * 2 + 0) * 1024 + l * 16]) = hv;
    *reinterpret_cast<f16x8*>(&buf[(wid * 2 + 1) * 1024 + l * 16]) = lo;
}

__device__ __forceinline__ void compute_step(const char* buf, int wr, int wc,
                                             int l, f32x4 (&acc)[4][4]) {
    const char* Ab = buf;
    const char* Bb = buf + 16384;
    f16x8 af[4][2], bf[4][2];
    #pragma unroll
    for (int mi = 0; mi < 4; ++mi)
        #pragma unroll
        for (int h = 0; h < 2; ++h)
            af[mi][h] = *reinterpret_cast<const f16x8*>(
                Ab + ((wr * 4 + mi) * 2 + h) * 1024 + l * 16);
    #pragma unroll
    for (int ni = 0; ni < 4; ++ni)
        #pragma unroll
        for (int h = 0; h < 2; ++h)
            bf[ni][h] = *reinterpret_cast<const f16x8*>(
                Bb + ((wc * 4 + ni) * 2 + h) * 1024 + l * 16);
    __builtin_amdgcn_s_setprio(1);
    #pragma unroll
    for (int mi = 0; mi < 4; ++mi)
        #pragma unroll
        for (int ni = 0; ni < 4; ++ni) {
            acc[mi][ni] = __builtin_amdgcn_mfma_f32_16x16x32_f16(
                af[mi][0], bf[ni][0], acc[mi][ni], 0, 0, 0);
            acc[mi][ni] = __builtin_amdgcn_mfma_f32_16x16x32_f16(
                af[mi][0], bf[ni][1], acc[mi][ni], 0, 0, 0);
            acc[mi][ni] = __builtin_amdgcn_mfma_f32_16x16x32_f16(
                af[mi][1], bf[ni][0], acc[mi][ni], 0, 0, 0);
        }
    __builtin_amdgcn_s_setprio(0);
}

// ---------------------------------------------------------------------------
// Kernel 2: split-K GEMM, f16 3-product fp32 emulation, depth-3 pipeline,
// raw barriers + counted vmcnt (R10 structure). Delta vs R10: write_A hoisted
// BEFORE compute_step (same inter-barrier region, disjoint buffers -> WAR-safe;
// ds_writes retire under the MFMA phase so the lgkmcnt(0) drain is free).
// ---------------------------------------------------------------------------
__global__ __launch_bounds__(512, 1)
void gemm_kernel(const float* __restrict__ x,
                 const f16* __restrict__ wpk,
                 float* __restrict__ partial) {
    __shared__ __align__(16) char lds[3][49152];   // 144 KiB

    const int tid = threadIdx.x;
    const int l   = tid & 63;
    const int wid = tid >> 6;
    const int bid = blockIdx.x;
    const int swz = (bid & 7) * 32 + (bid >> 3);   // XCD-chunked
    const int ks  = swz >> 6;       // 0..3
    const int mt  = swz & 63;       // 0..63
    const int wr  = wid >> 2;
    const int wc  = wid & 3;

    const int row = mt * BM + wid * 16 + (l & 15);
    const float* xrow = x + (size_t)row * H_DIM + ks * KSL + (l >> 4) * 8;
    const int kf0 = ks * NSTEP;

    f32x4 acc[4][4];
    #pragma unroll
    for (int mi = 0; mi < 4; ++mi)
        #pragma unroll
        for (int ni = 0; ni < 4; ++ni) acc[mi][ni] = (f32x4)0.0f;

    float4 pf0e, pf1e, pf0o, pf1o;

    // prologue: A(0)+B(0) into buf0, B(1) into buf1, x(1) into pf_o
    {
        float4 a00 = *reinterpret_cast<const float4*>(xrow);
        float4 a01 = *reinterpret_cast<const float4*>(xrow + 4);
        pf0o = *reinterpret_cast<const float4*>(xrow + BK);
        pf1o = *reinterpret_cast<const float4*>(xrow + BK + 4);
        stage_B(wpk, kf0 + 0, lds[0], wid, l);
        stage_B(wpk, kf0 + 1, lds[1], wid, l);
        write_A(lds[0], wid, l, a00, a01);
        asm volatile("s_waitcnt vmcnt(0) lgkmcnt(0)" ::: "memory");
        __builtin_amdgcn_sched_barrier(0);
        __builtin_amdgcn_s_barrier();
    }

    int cur = 0;
    for (int t = 0; t < NSTEP; t += 2) {
        int nx1 = cur + 1; if (nx1 == 3) nx1 = 0;
        int nx2 = nx1 + 1; if (nx2 == 3) nx2 = 0;

        // ---- step t (even): write A(t+1) early; compute buf[cur];
        //      issue x(t+2), B(t+2)
        if (t + 2 < NSTEP) {
            pf0e = *reinterpret_cast<const float4*>(xrow + (size_t)(t + 2) * BK);
            pf1e = *reinterpret_cast<const float4*>(xrow + (size_t)(t + 2) * BK + 4);
            stage_B(wpk, kf0 + t + 2, lds[nx2], wid, l);
            WAITVM(12);          // completes B(t); leaves x(t+1),B(t+1),x(t+2),B(t+2)
        } else {
            WAITVM(6);           // tail t==NSTEP-2: completes B(t)
        }
        write_A(lds[nx1], wid, l, pf0o, pf1o);     // A(t+1), hides under MFMA
        compute_step(lds[cur], wr, wc, l, acc);
        WAITLGKM0();
        __builtin_amdgcn_s_barrier();

        // ---- step t+1 (odd): write A(t+2) early; compute buf[nx1];
        //      issue x(t+3), B(t+3)
        if (t + 3 < NSTEP) {
            pf0o = *reinterpret_cast<const float4*>(xrow + (size_t)(t + 3) * BK);
            pf1o = *reinterpret_cast<const float4*>(xrow + (size_t)(t + 3) * BK + 4);
            stage_B(wpk, kf0 + t + 3, lds[cur], wid, l);   // (t+3)%3 == t%3
            WAITVM(12);
        } else {
            WAITVM(0);           // tail t+1==NSTEP-1
        }
        if (t + 2 < NSTEP)
            write_A(lds[nx2], wid, l, pf0e, pf1e); // A(t+2)
        compute_step(lds[nx1], wr, wc, l, acc);
        WAITLGKM0();
        __builtin_amdgcn_s_barrier();

        cur = nx2;
    }

    float* pbase = partial + ((size_t)ks * B_TOK + (size_t)mt * BM) * E_NUM;
    #pragma unroll
    for (int mi = 0; mi < 4; ++mi)
        #pragma unroll
        for (int ni = 0; ni < 4; ++ni)
            #pragma unroll
            for (int r = 0; r < 4; ++r) {
                int rr = wr * 64 + mi * 16 + (l >> 4) * 4 + r;
                int cc = wc * 64 + ni * 16 + (l & 15);
                pbase[(size_t)rr * E_NUM + cc] = acc[mi][ni][r];
            }
}

// ---------------------------------------------------------------------------
// Kernel 3: fast routing + margin flags.
// ---------------------------------------------------------------------------
__global__ __launch_bounds__(512, 1)
void routing_kernel(const float* __restrict__ partial,
                    const float* __restrict__ bias,
                    float* __restrict__ out,
                    unsigned* __restrict__ flags) {
    const int tid  = threadIdx.x;
    const int l    = tid & 63;
    const int wv   = tid >> 6;
    const int tok0 = blockIdx.x * 32;

    double bj[4];
    #pragma unroll
    for (int q = 0; q < 4; ++q) bj[q] = (double)bias[l + 64 * q];
    const int hf = l >> 5;

    for (int i = 0; i < 4; ++i) {
        const int t = tok0 + wv * 4 + i;
        double lv[4];
        #pragma unroll
        for (int q = 0; q < 4; ++q) {
            double s = 0.0;
            #pragma unroll
            for (int ksl = 0; ksl < NKS; ++ksl)
                s += (double)partial[((size_t)ksl * B_TOK + t) * E_NUM + l + 64 * q];
            lv[q] = s;
        }
        double ma, mg;
        route_token(lv, bj, l, hf, t, out, &ma, &mg);
        if (l == 0 && (ma < TAU || mg < TAU)) {
            unsigned idx = atomicAdd(&flags[0], 1u);
            if (idx < FLAG_CAP) flags[1 + idx] = (unsigned)t;
        }
    }
}

// ---------------------------------------------------------------------------
// Kernel 4: exact fp64 partial dots for flagged tokens.
// ---------------------------------------------------------------------------
__global__ __launch_bounds__(256)
void recompute_dot_kernel(const float* __restrict__ x,
                          const float* __restrict__ W,
                          const unsigned* __restrict__ flags,
                          double* __restrict__ dpart) {
    __shared__ float xs[896];
    unsigned count = flags[0]; if (count > FLAG_CAP) count = FLAG_CAP;
    unsigned nj = count * 8;
    for (unsigned j = blockIdx.x; j < nj; j += gridDim.x) {
        unsigned li = j >> 3, sl = j & 7;
        int t = (int)flags[1 + li];
        const float* xb = x + (size_t)t * H_DIM + sl * 896;
        for (int i = threadIdx.x; i < 224; i += 256)
            *reinterpret_cast<float4*>(&xs[i * 4]) =
                *reinterpret_cast<const float4*>(xb + i * 4);
        __syncthreads();
        const float* wp = W + (size_t)(sl * 896) * E_NUM + threadIdx.x;
        double acc = 0.0;
        #pragma unroll 8
        for (int k = 0; k < 896; ++k)
            acc += (double)xs[k] * (double)wp[(size_t)k * E_NUM];
        dpart[((size_t)li * 8 + sl) * E_NUM + threadIdx.x] = acc;
        __syncthreads();
    }
}

// ---------------------------------------------------------------------------
// Kernel 5: exact routing for flagged tokens (overwrites out).
// ---------------------------------------------------------------------------
__global__ __launch_bounds__(64)
void recompute_route_kernel(const double* __restrict__ dpart,
                            const float* __restrict__ bias,
                            const unsigned* __restrict__ flags,
                            float* __restrict__ out) {
    const int l = threadIdx.x;
    unsigned count = flags[0]; if (count > FLAG_CAP) count = FLAG_CAP;
    double bj[4];
    #pragma unroll
    for (int q = 0; q < 4; ++q) bj[q] = (double)bias[l + 64 * q];
    const int hf = l >> 5;
    for (unsigned li = blockIdx.x; li < count; li += gridDim.x) {
        int t = (int)flags[1 + li];
        double lv[4];
        #pragma unroll
        for (int q = 0; q < 4; ++q) {
            double s = 0.0;
            #pragma unroll
            for (int sl = 0; sl < 8; ++sl)
                s += dpart[((size_t)li * 8 + sl) * E_NUM + l + 64 * q];
            lv[q] = s;
        }
        double ma, mg;
        route_token(lv, bj, l, hf, t, out, &ma, &mg);
    }
}

// ---------------------------------------------------------------------------
// Fallback (round-1 verified fp64 kernel).
// ---------------------------------------------------------------------------
#define TM 32
#define HB 64
#define FNST (H_DIM / HB)

__global__ __launch_bounds__(512, 1)
void moe_gate_fallback(const float* __restrict__ x,
                       const float* __restrict__ W,
                       const float* __restrict__ bias,
                       float* __restrict__ out) {
    __shared__ double xs[TM][HB];
    const int tid  = threadIdx.x;
    const int l    = tid & 63;
    const int wv   = tid >> 6;
    const int tok0 = blockIdx.x * TM;
    const int tl = tid >> 4;
    const int ho = (tid & 15) * 4;

    double acc[4][4];
    #pragma unroll
    for (int i = 0; i < 4; ++i)
        #pragma unroll
        for (int q = 0; q < 4; ++q) acc[i][q] = 0.0;

    const float* xrow = x + (size_t)(tok0 + tl) * H_DIM + ho;
    float4 v = *reinterpret_cast<const float4*>(xrow);

    for (int s = 0; s < FNST; ++s) {
        __syncthreads();
        xs[tl][ho + 0] = (double)v.x;
        xs[tl][ho + 1] = (double)v.y;
        xs[tl][ho + 2] = (double)v.z;
        xs[tl][ho + 3] = (double)v.w;
        __syncthreads();
        const int sn = (s + 1 < FNST) ? s + 1 : s;
        v = *reinterpret_cast<const float4*>(xrow + (size_t)sn * HB);
        const float* wh = W + (size_t)s * HB * E_NUM + l;
        #pragma unroll 4
        for (int h = 0; h < HB; h += 2) {
            float wf0[4], wf1[4];
            #pragma unroll
            for (int q = 0; q < 4; ++q) {
                wf0[q] = wh[(size_t)h       * E_NUM + q * 64];
                wf1[q] = wh[(size_t)(h + 1) * E_NUM + q * 64];
            }
            #pragma unroll
            for (int i = 0; i < 4; ++i) {
                const double2 xv = *reinterpret_cast<const double2*>(&xs[wv * 4 + i][h]);
                #pragma unroll
                for (int q = 0; q < 4; ++q) {
                    acc[i][q] = fma((double)wf0[q], xv.x, acc[i][q]);
                    acc[i][q] = fma((double)wf1[q], xv.y, acc[i][q]);
                }
            }
        }
    }

    double bj[4];
    #pragma unroll
    for (int q = 0; q < 4; ++q) bj[q] = (double)bias[l + 64 * q];
    const int hf = l >> 5;

    for (int i = 0; i < 4; ++i) {
        const int t = tok0 + wv * 4 + i;
        double lv[4];
        #pragma unroll
        for (int q = 0; q < 4; ++q) lv[q] = acc[i][q];
        double ma, mg;
        route_token(lv, bj, l, hf, t, out, &ma, &mg);
    }
}

// ---------------------------------------------------------------------------
extern "C" void kernel_launch(void* const* d_in, const int* in_sizes, int n_in,
                              void* d_out, int out_size, void* d_ws, size_t ws_size,
                              hipStream_t stream) {
    const float* x    = (const float*)d_in[0];
    const float* W    = (const float*)d_in[1];
    const float* bias = (const float*)d_in[2];
    float* out = (float*)d_out;

    const size_t flag_off = 7864320;                  // after 7 MB wpk
    const size_t part_off = 8u * 1024 * 1024;
    const size_t need     = part_off + (size_t)NKS * B_TOK * E_NUM * 4;

    if (ws_size >= need) {
        f16*      wpk     = (f16*)d_ws;
        unsigned* flags   = (unsigned*)((char*)d_ws + flag_off);
        float*    partial = (float*)((char*)d_ws + part_off);
        double*   dpart   = (double*)((char*)d_ws + part_off);   // reused after routing

        convert_w_kernel<<<896, 256, 0, stream>>>(W, wpk, flags);
        gemm_kernel<<<NMT * NKS, 512, 0, stream>>>(x, wpk, partial);
        routing_kernel<<<B_TOK / 32, 512, 0, stream>>>(partial, bias, out, flags);
        recompute_dot_kernel<<<512, 256, 0, stream>>>(x, W, flags, dpart);
        recompute_route_kernel<<<64, 64, 0, stream>>>(dpart, bias, flags, out);
    } else {
        moe_gate_fallback<<<B_TOK / 32, 512, 0, stream>>>(x, W, bias, out);
    }
}

// Round 15
// 199.288 us; speedup vs baseline: 1.1505x; 1.1505x over previous
//
#include <hip/hip_runtime.h>
#include <math.h>

#define B_TOK 8192
#define H_DIM 7168
#define E_NUM 256
#define NKS   4
#define KSL   (H_DIM / NKS)    // 1792
#define BK    32
#define NSTEP (KSL / BK)       // 56 (even)
#define BM    128
#define NMT   (B_TOK / BM)     // 64
#define FLAG_CAP 512
#define TAU   2e-6

typedef _Float16 f16;
typedef __attribute__((ext_vector_type(8))) _Float16 f16x8;
typedef __attribute__((ext_vector_type(4))) float    f32x4;

typedef __attribute__((address_space(1))) const void gvoid_t;
typedef __attribute__((address_space(3))) void       lvoid_t;

__device__ inline void gload_lds16(const void* g, void* s) {
    __builtin_amdgcn_global_load_lds((gvoid_t*)g, (lvoid_t*)s, 16, 0, 0);
}

#define WAITVM(N) do { asm volatile("s_waitcnt vmcnt(" #N ")" ::: "memory"); \
                       __builtin_amdgcn_sched_barrier(0); } while (0)
#define WAITLGKM0() do { asm volatile("s_waitcnt lgkmcnt(0)" ::: "memory"); \
                       __builtin_amdgcn_sched_barrier(0); } while (0)

// ---------------------------------------------------------------------------
// Shared routing math (fp64, verified) + decision margins.
// ---------------------------------------------------------------------------
__device__ __forceinline__ void route_token(
    const double* lv, const double* bj, int l, int hf, int t,
    float* __restrict__ out, double* ming_adj, double* ming_grp)
{
    double m = fmax(fmax(lv[0], lv[1]), fmax(lv[2], lv[3]));
    #pragma unroll
    for (int d = 1; d < 64; d <<= 1) m = fmax(m, __shfl_xor(m, d, 64));
    double sc[4], zs = 0.0;
    #pragma unroll
    for (int q = 0; q < 4; ++q) { sc[q] = exp(lv[q] - m); zs += sc[q]; }
    #pragma unroll
    for (int d = 1; d < 64; d <<= 1) zs += __shfl_xor(zs, d, 64);
    double swb[4];
    #pragma unroll
    for (int q = 0; q < 4; ++q) { sc[q] /= zs; swb[q] = sc[q] + bj[q]; }

    double gsq[4];
    #pragma unroll
    for (int q = 0; q < 4; ++q) {
        double a = swb[q], b = -INFINITY;
        #pragma unroll
        for (int d = 1; d <= 16; d <<= 1) {
            double oa = __shfl_xor(a, d, 64), ob = __shfl_xor(b, d, 64);
            double na = fmax(a, oa);
            double nb = fmax(fmin(a, oa), fmax(b, ob));
            a = na; b = nb;
        }
        gsq[q] = a + b;
    }
    double gsv[8];
    #pragma unroll
    for (int q = 0; q < 4; ++q) {
        gsv[2 * q]     = __shfl(gsq[q], 0, 64);
        gsv[2 * q + 1] = __shfl(gsq[q], 32, 64);
    }

    unsigned selmask = 0; double g4 = 0.0, g5 = 0.0;
    #pragma unroll
    for (int k = 0; k < 5; ++k) {
        double best = -INFINITY; int bg = 0;
        #pragma unroll
        for (int g = 0; g < 8; ++g)
            if (gsv[g] > best) { best = gsv[g]; bg = g; }
        if (k < 4) { selmask |= 1u << bg; g4 = best; } else g5 = best;
        #pragma unroll
        for (int g = 0; g < 8; ++g) if (g == bg) gsv[g] = -INFINITY;
    }
    *ming_grp = g4 - g5;

    double mk[4];
    #pragma unroll
    for (int q = 0; q < 4; ++q)
        mk[q] = ((selmask >> (2 * q + hf)) & 1u) ? swb[q] : -INFINITY;

    double wk[8]; int ek[8]; double wsum = 0.0;
    double prev = 0.0, ming = 1e300;
    #pragma unroll
    for (int k = 0; k < 9; ++k) {
        double vbest = mk[0]; int ebest = l;
        #pragma unroll
        for (int q = 1; q < 4; ++q)
            if (mk[q] > vbest) { vbest = mk[q]; ebest = l + 64 * q; }
        #pragma unroll
        for (int d = 1; d < 64; d <<= 1) {
            double ov = __shfl_xor(vbest, d, 64);
            int    oe = __shfl_xor(ebest, d, 64);
            if (ov > vbest || (ov == vbest && oe < ebest)) { vbest = ov; ebest = oe; }
        }
        if (k > 0) ming = fmin(ming, prev - vbest);
        prev = vbest;
        if (k < 8) {
            const int ol = ebest & 63, oq = ebest >> 6;
            if (l == ol) {
                #pragma unroll
                for (int q = 0; q < 4; ++q) if (q == oq) mk[q] = -INFINITY;
            }
            double cand = (oq == 0) ? sc[0] : (oq == 1) ? sc[1] : (oq == 2) ? sc[2] : sc[3];
            double sv = __shfl(cand, ol, 64);
            wk[k] = sv; ek[k] = ebest; wsum += sv;
        }
    }
    *ming_adj = ming;

    if (l == 0) {
        const double inv = 1.0 / wsum;
        #pragma unroll
        for (int k = 0; k < 8; ++k) {
            out[(size_t)t * 8 + k] = (float)((wk[k] * inv + 1e-20) * 2.5);
            out[(size_t)B_TOK * 8 + (size_t)t * 8 + k] = (float)ek[k];
        }
    }
}

// ---------------------------------------------------------------------------
// Kernel 1: pack W -> MFMA-B-fragment-ordered f16 hi/lo, COALESCED writes.
// Thread (fgp = kf*16+nf, lane l): reads 8 strided W vals, writes 16 B hi +
// 16 B lo contiguous. off = ((kf*16+nf)*2+h)*512 + l*8 + j.
// ---------------------------------------------------------------------------
__global__ void convert_w_kernel(const float* __restrict__ W,
                                 f16* __restrict__ wpk,
                                 unsigned* __restrict__ flags) {
    if (blockIdx.x == 0 && threadIdx.x == 0) flags[0] = 0;
    int gid = blockIdx.x * 256 + threadIdx.x;     // 0 .. 3584*64-1
    int fgp = gid >> 6;                           // kf*16 + nf
    int l   = gid & 63;
    int kf = fgp >> 4, nf = fgp & 15;
    int rb  = kf * 32 + (l >> 4) * 8;
    int col = nf * 16 + (l & 15);
    f16x8 hv, lv;
    #pragma unroll
    for (int j = 0; j < 8; ++j) {
        float v = W[(size_t)(rb + j) * E_NUM + col];
        f16 hh = (f16)v;
        hv[j] = hh;
        lv[j] = (f16)(v - (float)hh);
    }
    *reinterpret_cast<f16x8*>(&wpk[(size_t)fgp * 1024 + l * 8])       = hv;
    *reinterpret_cast<f16x8*>(&wpk[(size_t)fgp * 1024 + 512 + l * 8]) = lv;
}

// ---------------------------------------------------------------------------
// GEMM helpers (R10 verified-best structure: setprio ON per R10-vs-R13 A/B
// [135 vs 146 us]; write_A AFTER compute_step per R10-vs-R14 A/B
// [135 vs 160 us])
// ---------------------------------------------------------------------------
__device__ __forceinline__ void stage_B(const f16* __restrict__ wpk, int kf,
                                        char* bbuf, int wid, int l) {
    #pragma unroll
    for (int i = 0; i < 4; ++i) {
        int fi = wid * 4 + i, nf = fi >> 1, h = fi & 1;
        const f16* src = wpk + ((size_t)(kf * 16 + nf) * 2 + h) * 512 + (size_t)l * 8;
        gload_lds16(src, bbuf + 16384 + (nf * 2 + h) * 1024);
    }
}

__device__ __forceinline__ void write_A(char* buf, int wid, int l,
                                        float4 a0, float4 a1) {
    float fv[8] = {a0.x, a0.y, a0.z, a0.w, a1.x, a1.y, a1.z, a1.w};
    f16x8 hv, lo;
    #pragma unroll
    for (int j = 0; j < 8; ++j) {
        f16 hh = (f16)fv[j];
        hv[j] = hh;
        lo[j] = (f16)(fv[j] - (float)hh);
    }
    *reinterpret_cast<f16x8*>(&buf[(wid * 2 + 0) * 1024 + l * 16]) = hv;
    *reinterpret_cast<f16x8*>(&buf[(wid * 2 + 1) * 1024 + l * 16]) = lo;
}

__device__ __forceinline__ void compute_step(const char* buf, int wr, int wc,
                                             int l, f32x4 (&acc)[4][4]) {
    const char* Ab = buf;
    const char* Bb = buf + 16384;
    f16x8 af[4][2], bf[4][2];
    #pragma unroll
    for (int mi = 0; mi < 4; ++mi)
        #pragma unroll
        for (int h = 0; h < 2; ++h)
            af[mi][h] = *reinterpret_cast<const f16x8*>(
                Ab + ((wr * 4 + mi) * 2 + h) * 1024 + l * 16);
    #pragma unroll
    for (int ni = 0; ni < 4; ++ni)
        #pragma unroll
        for (int h = 0; h < 2; ++h)
            bf[ni][h] = *reinterpret_cast<const f16x8*>(
                Bb + ((wc * 4 + ni) * 2 + h) * 1024 + l * 16);
    __builtin_amdgcn_s_setprio(1);
    #pragma unroll
    for (int mi = 0; mi < 4; ++mi)
        #pragma unroll
        for (int ni = 0; ni < 4; ++ni) {
            acc[mi][ni] = __builtin_amdgcn_mfma_f32_16x16x32_f16(
                af[mi][0], bf[ni][0], acc[mi][ni], 0, 0, 0);
            acc[mi][ni] = __builtin_amdgcn_mfma_f32_16x16x32_f16(
                af[mi][0], bf[ni][1], acc[mi][ni], 0, 0, 0);
            acc[mi][ni] = __builtin_amdgcn_mfma_f32_16x16x32_f16(
                af[mi][1], bf[ni][0], acc[mi][ni], 0, 0, 0);
        }
    __builtin_amdgcn_s_setprio(0);
}

// ---------------------------------------------------------------------------
// Kernel 2: split-K GEMM, f16 3-product fp32 emulation, depth-3 pipeline,
// raw barriers + counted vmcnt (R10 verbatim, measured 135-137 us best-known).
// ---------------------------------------------------------------------------
__global__ __launch_bounds__(512, 1)
void gemm_kernel(const float* __restrict__ x,
                 const f16* __restrict__ wpk,
                 float* __restrict__ partial) {
    __shared__ __align__(16) char lds[3][49152];   // 144 KiB

    const int tid = threadIdx.x;
    const int l   = tid & 63;
    const int wid = tid >> 6;
    const int bid = blockIdx.x;
    const int swz = (bid & 7) * 32 + (bid >> 3);   // XCD-chunked
    const int ks  = swz >> 6;       // 0..3
    const int mt  = swz & 63;       // 0..63
    const int wr  = wid >> 2;
    const int wc  = wid & 3;

    const int row = mt * BM + wid * 16 + (l & 15);
    const float* xrow = x + (size_t)row * H_DIM + ks * KSL + (l >> 4) * 8;
    const int kf0 = ks * NSTEP;

    f32x4 acc[4][4];
    #pragma unroll
    for (int mi = 0; mi < 4; ++mi)
        #pragma unroll
        for (int ni = 0; ni < 4; ++ni) acc[mi][ni] = (f32x4)0.0f;

    float4 pf0e, pf1e, pf0o, pf1o;

    // prologue: A(0)+B(0) into buf0, B(1) into buf1, x(1) into pf_o
    {
        float4 a00 = *reinterpret_cast<const float4*>(xrow);
        float4 a01 = *reinterpret_cast<const float4*>(xrow + 4);
        pf0o = *reinterpret_cast<const float4*>(xrow + BK);
        pf1o = *reinterpret_cast<const float4*>(xrow + BK + 4);
        stage_B(wpk, kf0 + 0, lds[0], wid, l);
        stage_B(wpk, kf0 + 1, lds[1], wid, l);
        write_A(lds[0], wid, l, a00, a01);
        asm volatile("s_waitcnt vmcnt(0) lgkmcnt(0)" ::: "memory");
        __builtin_amdgcn_sched_barrier(0);
        __builtin_amdgcn_s_barrier();
    }

    int cur = 0;
    for (int t = 0; t < NSTEP; t += 2) {
        int nx1 = cur + 1; if (nx1 == 3) nx1 = 0;
        int nx2 = nx1 + 1; if (nx2 == 3) nx2 = 0;

        // ---- step t (even): compute buf[cur]; consume pf_o=x(t+1); issue x(t+2),B(t+2)
        if (t + 2 < NSTEP) {
            pf0e = *reinterpret_cast<const float4*>(xrow + (size_t)(t + 2) * BK);
            pf1e = *reinterpret_cast<const float4*>(xrow + (size_t)(t + 2) * BK + 4);
            stage_B(wpk, kf0 + t + 2, lds[nx2], wid, l);
            WAITVM(12);          // completes B(t); leaves x(t+1),B(t+1),x(t+2),B(t+2)
        } else {
            WAITVM(6);           // tail t==NSTEP-2: completes B(t)
        }
        compute_step(lds[cur], wr, wc, l, acc);
        write_A(lds[nx1], wid, l, pf0o, pf1o);     // A(t+1)
        WAITLGKM0();
        __builtin_amdgcn_s_barrier();

        // ---- step t+1 (odd): compute buf[nx1]; consume pf_e=x(t+2); issue x(t+3),B(t+3)
        if (t + 3 < NSTEP) {
            pf0o = *reinterpret_cast<const float4*>(xrow + (size_t)(t + 3) * BK);
            pf1o = *reinterpret_cast<const float4*>(xrow + (size_t)(t + 3) * BK + 4);
            stage_B(wpk, kf0 + t + 3, lds[cur], wid, l);   // (t+3)%3 == t%3
            WAITVM(12);
        } else {
            WAITVM(0);           // tail t+1==NSTEP-1
        }
        compute_step(lds[nx1], wr, wc, l, acc);
        if (t + 2 < NSTEP)
            write_A(lds[nx2], wid, l, pf0e, pf1e); // A(t+2)
        WAITLGKM0();
        __builtin_amdgcn_s_barrier();

        cur = nx2;
    }

    float* pbase = partial + ((size_t)ks * B_TOK + (size_t)mt * BM) * E_NUM;
    #pragma unroll
    for (int mi = 0; mi < 4; ++mi)
        #pragma unroll
        for (int ni = 0; ni < 4; ++ni)
            #pragma unroll
            for (int r = 0; r < 4; ++r) {
                int rr = wr * 64 + mi * 16 + (l >> 4) * 4 + r;
                int cc = wc * 64 + ni * 16 + (l & 15);
                pbase[(size_t)rr * E_NUM + cc] = acc[mi][ni][r];
            }
}

// ---------------------------------------------------------------------------
// Kernel 3: fast routing + margin flags.
// ---------------------------------------------------------------------------
__global__ __launch_bounds__(512, 1)
void routing_kernel(const float* __restrict__ partial,
                    const float* __restrict__ bias,
                    float* __restrict__ out,
                    unsigned* __restrict__ flags) {
    const int tid  = threadIdx.x;
    const int l    = tid & 63;
    const int wv   = tid >> 6;
    const int tok0 = blockIdx.x * 32;

    double bj[4];
    #pragma unroll
    for (int q = 0; q < 4; ++q) bj[q] = (double)bias[l + 64 * q];
    const int hf = l >> 5;

    for (int i = 0; i < 4; ++i) {
        const int t = tok0 + wv * 4 + i;
        double lv[4];
        #pragma unroll
        for (int q = 0; q < 4; ++q) {
            double s = 0.0;
            #pragma unroll
            for (int ksl = 0; ksl < NKS; ++ksl)
                s += (double)partial[((size_t)ksl * B_TOK + t) * E_NUM + l + 64 * q];
            lv[q] = s;
        }
        double ma, mg;
        route_token(lv, bj, l, hf, t, out, &ma, &mg);
        if (l == 0 && (ma < TAU || mg < TAU)) {
            unsigned idx = atomicAdd(&flags[0], 1u);
            if (idx < FLAG_CAP) flags[1 + idx] = (unsigned)t;
        }
    }
}

// ---------------------------------------------------------------------------
// Kernel 4: exact fp64 partial dots for flagged tokens.
// ---------------------------------------------------------------------------
__global__ __launch_bounds__(256)
void recompute_dot_kernel(const float* __restrict__ x,
                          const float* __restrict__ W,
                          const unsigned* __restrict__ flags,
                          double* __restrict__ dpart) {
    __shared__ float xs[896];
    unsigned count = flags[0]; if (count > FLAG_CAP) count = FLAG_CAP;
    unsigned nj = count * 8;
    for (unsigned j = blockIdx.x; j < nj; j += gridDim.x) {
        unsigned li = j >> 3, sl = j & 7;
        int t = (int)flags[1 + li];
        const float* xb = x + (size_t)t * H_DIM + sl * 896;
        for (int i = threadIdx.x; i < 224; i += 256)
            *reinterpret_cast<float4*>(&xs[i * 4]) =
                *reinterpret_cast<const float4*>(xb + i * 4);
        __syncthreads();
        const float* wp = W + (size_t)(sl * 896) * E_NUM + threadIdx.x;
        double acc = 0.0;
        #pragma unroll 8
        for (int k = 0; k < 896; ++k)
            acc += (double)xs[k] * (double)wp[(size_t)k * E_NUM];
        dpart[((size_t)li * 8 + sl) * E_NUM + threadIdx.x] = acc;
        __syncthreads();
    }
}

// ---------------------------------------------------------------------------
// Kernel 5: exact routing for flagged tokens (overwrites out).
// ---------------------------------------------------------------------------
__global__ __launch_bounds__(64)
void recompute_route_kernel(const double* __restrict__ dpart,
                            const float* __restrict__ bias,
                            const unsigned* __restrict__ flags,
                            float* __restrict__ out) {
    const int l = threadIdx.x;
    unsigned count = flags[0]; if (count > FLAG_CAP) count = FLAG_CAP;
    double bj[4];
    #pragma unroll
    for (int q = 0; q < 4; ++q) bj[q] = (double)bias[l + 64 * q];
    const int hf = l >> 5;
    for (unsigned li = blockIdx.x; li < count; li += gridDim.x) {
        int t = (int)flags[1 + li];
        double lv[4];
        #pragma unroll
        for (int q = 0; q < 4; ++q) {
            double s = 0.0;
            #pragma unroll
            for (int sl = 0; sl < 8; ++sl)
                s += dpart[((size_t)li * 8 + sl) * E_NUM + l + 64 * q];
            lv[q] = s;
        }
        double ma, mg;
        route_token(lv, bj, l, hf, t, out, &ma, &mg);
    }
}

// ---------------------------------------------------------------------------
// Fallback (round-1 verified fp64 kernel).
// ---------------------------------------------------------------------------
#define TM 32
#define HB 64
#define FNST (H_DIM / HB)

__global__ __launch_bounds__(512, 1)
void moe_gate_fallback(const float* __restrict__ x,
                       const float* __restrict__ W,
                       const float* __restrict__ bias,
                       float* __restrict__ out) {
    __shared__ double xs[TM][HB];
    const int tid  = threadIdx.x;
    const int l    = tid & 63;
    const int wv   = tid >> 6;
    const int tok0 = blockIdx.x * TM;
    const int tl = tid >> 4;
    const int ho = (tid & 15) * 4;

    double acc[4][4];
    #pragma unroll
    for (int i = 0; i < 4; ++i)
        #pragma unroll
        for (int q = 0; q < 4; ++q) acc[i][q] = 0.0;

    const float* xrow = x + (size_t)(tok0 + tl) * H_DIM + ho;
    float4 v = *reinterpret_cast<const float4*>(xrow);

    for (int s = 0; s < FNST; ++s) {
        __syncthreads();
        xs[tl][ho + 0] = (double)v.x;
        xs[tl][ho + 1] = (double)v.y;
        xs[tl][ho + 2] = (double)v.z;
        xs[tl][ho + 3] = (double)v.w;
        __syncthreads();
        const int sn = (s + 1 < FNST) ? s + 1 : s;
        v = *reinterpret_cast<const float4*>(xrow + (size_t)sn * HB);
        const float* wh = W + (size_t)s * HB * E_NUM + l;
        #pragma unroll 4
        for (int h = 0; h < HB; h += 2) {
            float wf0[4], wf1[4];
            #pragma unroll
            for (int q = 0; q < 4; ++q) {
                wf0[q] = wh[(size_t)h       * E_NUM + q * 64];
                wf1[q] = wh[(size_t)(h + 1) * E_NUM + q * 64];
            }
            #pragma unroll
            for (int i = 0; i < 4; ++i) {
                const double2 xv = *reinterpret_cast<const double2*>(&xs[wv * 4 + i][h]);
                #pragma unroll
                for (int q = 0; q < 4; ++q) {
                    acc[i][q] = fma((double)wf0[q], xv.x, acc[i][q]);
                    acc[i][q] = fma((double)wf1[q], xv.y, acc[i][q]);
                }
            }
        }
    }

    double bj[4];
    #pragma unroll
    for (int q = 0; q < 4; ++q) bj[q] = (double)bias[l + 64 * q];
    const int hf = l >> 5;

    for (int i = 0; i < 4; ++i) {
        const int t = tok0 + wv * 4 + i;
        double lv[4];
        #pragma unroll
        for (int q = 0; q < 4; ++q) lv[q] = acc[i][q];
        double ma, mg;
        route_token(lv, bj, l, hf, t, out, &ma, &mg);
    }
}

// ---------------------------------------------------------------------------
extern "C" void kernel_launch(void* const* d_in, const int* in_sizes, int n_in,
                              void* d_out, int out_size, void* d_ws, size_t ws_size,
                              hipStream_t stream) {
    const float* x    = (const float*)d_in[0];
    const float* W    = (const float*)d_in[1];
    const float* bias = (const float*)d_in[2];
    float* out = (float*)d_out;

    const size_t flag_off = 7864320;                  // after 7 MB wpk
    const size_t part_off = 8u * 1024 * 1024;
    const size_t need     = part_off + (size_t)NKS * B_TOK * E_NUM * 4;

    if (ws_size >= need) {
        f16*      wpk     = (f16*)d_ws;
        unsigned* flags   = (unsigned*)((char*)d_ws + flag_off);
        float*    partial = (float*)((char*)d_ws + part_off);
        double*   dpart   = (double*)((char*)d_ws + part_off);   // reused after routing

        convert_w_kernel<<<896, 256, 0, stream>>>(W, wpk, flags);
        gemm_kernel<<<NMT * NKS, 512, 0, stream>>>(x, wpk, partial);
        routing_kernel<<<B_TOK / 32, 512, 0, stream>>>(partial, bias, out, flags);
        recompute_dot_kernel<<<512, 256, 0, stream>>>(x, W, flags, dpart);
        recompute_route_kernel<<<64, 64, 0, stream>>>(dpart, bias, flags, out);
    } else {
        moe_gate_fallback<<<B_TOK / 32, 512, 0, stream>>>(x, W, bias, out);
    }
}